// Round 1
// baseline (682.316 us; speedup 1.0000x reference)
//
#include <hip/hip_runtime.h>
#include <cstdint>
#include <cstddef>

// ---------------------------------------------------------------------------
// GCN encoder: z = GCN3( relu(GCN2( relu(GCN1( LN(x) )) )) )
// GCNk(h) = dinv[d] * sum_{e: dst=d} dinv[src_e] * (h W)[src_e]
//           + dinv[d]^2 * (h W)[d] + b
// Strategy: build CSR by dst (counting sort) once per launch; aggregation is
// one wave per dst node (no atomics on features). GEMMs are fp32 LDS-tiled.
// ---------------------------------------------------------------------------

__global__ void zero_i32(int* __restrict__ p, int n) {
  int i = blockIdx.x * 256 + threadIdx.x;
  if (i < n) p[i] = 0;
}

__global__ void count_deg(const int* __restrict__ dst, int* __restrict__ cnt, int E) {
  int e = blockIdx.x * 256 + threadIdx.x;
  if (e < E) atomicAdd(&cnt[dst[e]], 1);
}

// per-1024 block inclusive scan -> local exclusive + block sums
__global__ void scan_local(const int* __restrict__ cnt, int* __restrict__ loc,
                           int* __restrict__ bsum, int n) {
  __shared__ int tmp[1024];
  int tid = threadIdx.x;
  int gid = blockIdx.x * 1024 + tid;
  int v = (gid < n) ? cnt[gid] : 0;
  tmp[tid] = v;
  __syncthreads();
  for (int off = 1; off < 1024; off <<= 1) {
    int t = (tid >= off) ? tmp[tid - off] : 0;
    __syncthreads();
    tmp[tid] += t;
    __syncthreads();
  }
  if (gid < n) loc[gid] = tmp[tid] - v;  // exclusive
  if (tid == 1023) bsum[blockIdx.x] = tmp[1023];
}

__global__ void scan_spine(int* __restrict__ bsum, int nb) {
  if (threadIdx.x == 0 && blockIdx.x == 0) {
    int run = 0;
    for (int i = 0; i < nb; ++i) { int v = bsum[i]; bsum[i] = run; run += v; }
  }
}

__global__ void finalize_csr(const int* __restrict__ cnt, const int* __restrict__ loc,
                             const int* __restrict__ bsum, int* __restrict__ offs,
                             int* __restrict__ cursor, float* __restrict__ dinv,
                             int n, int E) {
  int i = blockIdx.x * 256 + threadIdx.x;
  if (i < n) {
    int o = loc[i] + bsum[i >> 10];
    offs[i] = o;
    cursor[i] = o;
    dinv[i] = rsqrtf(1.0f + (float)cnt[i]);
  }
  if (i == 0) offs[n] = E;
}

__global__ void place_edges(const int* __restrict__ src, const int* __restrict__ dst,
                            const float* __restrict__ dinv, int* __restrict__ cursor,
                            int* __restrict__ srcs, float* __restrict__ wsrc, int E) {
  int e = blockIdx.x * 256 + threadIdx.x;
  if (e < E) {
    int d = dst[e], s = src[e];
    int slot = atomicAdd(&cursor[d], 1);
    srcs[slot] = s;
    wsrc[slot] = dinv[s];
  }
}

// one wave per row: mean / rsqrt(var+eps) over 256 fp32
__global__ void ln_stats(const float* __restrict__ x, float* __restrict__ mu,
                         float* __restrict__ rs, int n) {
  int gid = blockIdx.x * blockDim.x + threadIdx.x;
  int wv = gid >> 6, lane = gid & 63;
  if (wv >= n) return;
  const float4* row = (const float4*)(x + (size_t)wv * 256);
  float4 v = row[lane];
  float s = v.x + v.y + v.z + v.w;
  float s2 = v.x * v.x + v.y * v.y + v.z * v.z + v.w * v.w;
  for (int off = 32; off > 0; off >>= 1) {
    s += __shfl_down(s, off);
    s2 += __shfl_down(s2, off);
  }
  if (lane == 0) {
    float m = s * (1.0f / 256.0f);
    float var = s2 * (1.0f / 256.0f) - m * m;
    mu[wv] = m;
    rs[wv] = rsqrtf(var + 1e-5f);
  }
}

// fp32 tiled GEMM: out[nrows x NOUT] = A[nrows x K] * W[K x NOUT]
// optional fused layernorm on A (per-row mu/rs + gamma/beta per column)
template <int K, int NOUT, bool LN>
__launch_bounds__(256)
__global__ void gemm_tile(const float* __restrict__ A, const float* __restrict__ W,
                          const float* __restrict__ mu, const float* __restrict__ rs,
                          const float* __restrict__ gamma, const float* __restrict__ beta,
                          float* __restrict__ out, int nrows) {
  constexpr int BM = 64, BK = 32;
  constexpr int TM = 4, TN = NOUT / 16;
  __shared__ float Ast[BK][BM + 1];  // transposed A tile, padded (65 % 32 = 1)
  __shared__ float Bs[BK][NOUT];
  int tid = threadIdx.x;
  int row0 = blockIdx.x * BM;
  int col_t = tid & 15, row_t = tid >> 4;
  float acc[TM][TN];
#pragma unroll
  for (int m = 0; m < TM; m++)
#pragma unroll
    for (int n = 0; n < TN; n++) acc[m][n] = 0.f;

  for (int k0 = 0; k0 < K; k0 += BK) {
#pragma unroll
    for (int i = 0; i < (BM * BK) / 256; ++i) {
      int idx = i * 256 + tid;
      int r = idx / BK, c = idx % BK;
      int grow = row0 + r, gcol = k0 + c;
      float v = 0.f;
      if (grow < nrows) {
        v = A[(size_t)grow * K + gcol];
        if (LN) v = (v - mu[grow]) * rs[grow] * gamma[gcol] + beta[gcol];
      }
      Ast[c][r] = v;
    }
#pragma unroll
    for (int i = 0; i < (BK * NOUT) / 256; ++i) {
      int idx = i * 256 + tid;
      int r = idx / NOUT, c = idx % NOUT;
      Bs[r][c] = W[(size_t)(k0 + r) * NOUT + c];
    }
    __syncthreads();
#pragma unroll
    for (int kk = 0; kk < BK; ++kk) {
      float a[TM], b[TN];
#pragma unroll
      for (int m = 0; m < TM; m++) a[m] = Ast[kk][row_t * TM + m];
#pragma unroll
      for (int n = 0; n < TN; n++) b[n] = Bs[kk][col_t * TN + n];
#pragma unroll
      for (int m = 0; m < TM; m++)
#pragma unroll
        for (int n = 0; n < TN; n++) acc[m][n] = fmaf(a[m], b[n], acc[m][n]);
    }
    __syncthreads();
  }
#pragma unroll
  for (int m = 0; m < TM; m++) {
    int grow = row0 + row_t * TM + m;
    if (grow < nrows) {
#pragma unroll
      for (int n = 0; n < TN; n++) out[(size_t)grow * NOUT + col_t * TN + n] = acc[m][n];
    }
  }
}

// one wave per dst node, D=128: lane holds float2 of the feature row
template <bool RELU>
__global__ void agg128(const float* __restrict__ t, const int* __restrict__ offs,
                       const int* __restrict__ srcs, const float* __restrict__ ws,
                       const float* __restrict__ dinv, const float* __restrict__ bias,
                       float* __restrict__ out, int n) {
  int gid = blockIdx.x * blockDim.x + threadIdx.x;
  int wv = gid >> 6, lane = gid & 63;
  if (wv >= n) return;
  int e0 = offs[wv], e1 = offs[wv + 1];
  float ax = 0.f, ay = 0.f;
  for (int e = e0; e < e1; ++e) {
    int s = srcs[e];
    float w = ws[e];
    const float2 v = *(const float2*)(t + ((size_t)s << 7) + lane * 2);
    ax = fmaf(w, v.x, ax);
    ay = fmaf(w, v.y, ay);
  }
  float di = dinv[wv];
  const float2 sv = *(const float2*)(t + ((size_t)wv << 7) + lane * 2);
  const float2 bv = *(const float2*)(bias + lane * 2);
  float ox = di * ax + di * di * sv.x + bv.x;
  float oy = di * ay + di * di * sv.y + bv.y;
  if (RELU) { ox = fmaxf(ox, 0.f); oy = fmaxf(oy, 0.f); }
  float2 o = {ox, oy};
  *(float2*)(out + ((size_t)wv << 7) + lane * 2) = o;
}

// one wave per dst node, D=64: lane holds one float
template <bool RELU>
__global__ void agg64(const float* __restrict__ t, const int* __restrict__ offs,
                      const int* __restrict__ srcs, const float* __restrict__ ws,
                      const float* __restrict__ dinv, const float* __restrict__ bias,
                      float* __restrict__ out, int n) {
  int gid = blockIdx.x * blockDim.x + threadIdx.x;
  int wv = gid >> 6, lane = gid & 63;
  if (wv >= n) return;
  int e0 = offs[wv], e1 = offs[wv + 1];
  float a = 0.f;
  for (int e = e0; e < e1; ++e) {
    int s = srcs[e];
    float w = ws[e];
    a = fmaf(w, t[((size_t)s << 6) + lane], a);
  }
  float di = dinv[wv];
  float v = di * a + di * di * t[((size_t)wv << 6) + lane] + bias[lane];
  if (RELU) v = fmaxf(v, 0.f);
  out[((size_t)wv << 6) + lane] = v;
}

extern "C" void kernel_launch(void* const* d_in, const int* in_sizes, int n_in,
                              void* d_out, int out_size, void* d_ws, size_t ws_size,
                              hipStream_t stream) {
  const float* x = (const float*)d_in[0];
  const int* ei = (const int*)d_in[1];
  const float* gamma = (const float*)d_in[2];
  const float* beta = (const float*)d_in[3];
  const float* W1 = (const float*)d_in[4];
  const float* b1 = (const float*)d_in[5];
  const float* W2 = (const float*)d_in[6];
  const float* b2 = (const float*)d_in[7];
  const float* W3 = (const float*)d_in[8];
  const float* b3 = (const float*)d_in[9];
  float* out = (float*)d_out;

  const int N = in_sizes[0] / 256;
  const int E = in_sizes[1] / 2;
  const int* src = ei;
  const int* dst = ei + E;

  // workspace carve-up (256B aligned), total ~59 MB
  char* ws = (char*)d_ws;
  auto alloc = [&](size_t bytes) -> char* {
    char* p = ws;
    ws += (bytes + 255) & ~(size_t)255;
    return p;
  };
  int* cnt = (int*)alloc((size_t)N * 4);
  int* loc = (int*)alloc((size_t)N * 4);
  int* bsum = (int*)alloc(1024 * 4);
  int* offs = (int*)alloc((size_t)(N + 1) * 4);
  int* cursor = (int*)alloc((size_t)N * 4);
  float* dinv = (float*)alloc((size_t)N * 4);
  int* srcs = (int*)alloc((size_t)E * 4);
  float* wsrc = (float*)alloc((size_t)E * 4);
  float* mu = (float*)alloc((size_t)N * 4);
  float* rs = (float*)alloc((size_t)N * 4);
  float* t = (float*)alloc((size_t)N * 128 * 4);
  float* h = (float*)alloc((size_t)N * 128 * 4);

  const int nb1024 = (N + 1023) / 1024;

  // ---- CSR build ----
  zero_i32<<<(N + 255) / 256, 256, 0, stream>>>(cnt, N);
  count_deg<<<(E + 255) / 256, 256, 0, stream>>>(dst, cnt, E);
  scan_local<<<nb1024, 1024, 0, stream>>>(cnt, loc, bsum, N);
  scan_spine<<<1, 64, 0, stream>>>(bsum, nb1024);
  finalize_csr<<<(N + 255) / 256, 256, 0, stream>>>(cnt, loc, bsum, offs, cursor, dinv, N, E);
  place_edges<<<(E + 255) / 256, 256, 0, stream>>>(src, dst, dinv, cursor, srcs, wsrc, E);

  // ---- layernorm stats ----
  ln_stats<<<(N + 3) / 4, 256, 0, stream>>>(x, mu, rs, N);

  const int gemm_blocks = (N + 63) / 64;
  const int agg_blocks = (N + 3) / 4;  // 4 waves per 256-thread block

  // ---- layer 1: t = LN(x) @ W1 ; h = relu(agg(t) + b1) ----
  gemm_tile<256, 128, true><<<gemm_blocks, 256, 0, stream>>>(x, W1, mu, rs, gamma, beta, t, N);
  agg128<true><<<agg_blocks, 256, 0, stream>>>(t, offs, srcs, wsrc, dinv, b1, h, N);

  // ---- layer 2: t = h @ W2 ; h = relu(agg(t) + b2) ----
  gemm_tile<128, 128, false><<<gemm_blocks, 256, 0, stream>>>(h, W2, nullptr, nullptr, nullptr, nullptr, t, N);
  agg128<true><<<agg_blocks, 256, 0, stream>>>(t, offs, srcs, wsrc, dinv, b2, h, N);

  // ---- layer 3: t = h @ W3 ; out = agg(t) + b3 ----
  gemm_tile<128, 64, false><<<gemm_blocks, 256, 0, stream>>>(h, W3, nullptr, nullptr, nullptr, nullptr, t, N);
  agg64<false><<<agg_blocks, 256, 0, stream>>>(t, offs, srcs, wsrc, dinv, b3, out, N);
}

// Round 2
// 517.561 us; speedup vs baseline: 1.3183x; 1.3183x over previous
//
#include <hip/hip_runtime.h>
#include <cstdint>
#include <cstddef>

// ---------------------------------------------------------------------------
// GCN encoder: z = GCN3( relu(GCN2( relu(GCN1( LN(x) )) )) )
// GCNk(h) = dinv[d] * sum_{e: dst=d} dinv[src_e] * (h W)[src_e]
//           + dinv[d]^2 * (h W)[d] + b
// R2: GEMMs via bf16x3 split-precision MFMA (fp32-equivalent accuracy).
//     CSR build + wave-per-node gather aggregation unchanged from R1.
// ---------------------------------------------------------------------------

typedef __attribute__((ext_vector_type(8))) __bf16 bf16x8;
typedef __attribute__((ext_vector_type(4))) float f32x4;

__global__ void zero_i32(int* __restrict__ p, int n) {
  int i = blockIdx.x * 256 + threadIdx.x;
  if (i < n) p[i] = 0;
}

__global__ void count_deg(const int* __restrict__ dst, int* __restrict__ cnt, int E) {
  int e = blockIdx.x * 256 + threadIdx.x;
  if (e < E) atomicAdd(&cnt[dst[e]], 1);
}

__global__ void scan_local(const int* __restrict__ cnt, int* __restrict__ loc,
                           int* __restrict__ bsum, int n) {
  __shared__ int tmp[1024];
  int tid = threadIdx.x;
  int gid = blockIdx.x * 1024 + tid;
  int v = (gid < n) ? cnt[gid] : 0;
  tmp[tid] = v;
  __syncthreads();
  for (int off = 1; off < 1024; off <<= 1) {
    int t = (tid >= off) ? tmp[tid - off] : 0;
    __syncthreads();
    tmp[tid] += t;
    __syncthreads();
  }
  if (gid < n) loc[gid] = tmp[tid] - v;  // exclusive
  if (tid == 1023) bsum[blockIdx.x] = tmp[1023];
}

__global__ void scan_spine(int* __restrict__ bsum, int nb) {
  if (threadIdx.x == 0 && blockIdx.x == 0) {
    int run = 0;
    for (int i = 0; i < nb; ++i) { int v = bsum[i]; bsum[i] = run; run += v; }
  }
}

__global__ void finalize_csr(const int* __restrict__ cnt, const int* __restrict__ loc,
                             const int* __restrict__ bsum, int* __restrict__ offs,
                             int* __restrict__ cursor, float* __restrict__ dinv,
                             int n, int E) {
  int i = blockIdx.x * 256 + threadIdx.x;
  if (i < n) {
    int o = loc[i] + bsum[i >> 10];
    offs[i] = o;
    cursor[i] = o;
    dinv[i] = rsqrtf(1.0f + (float)cnt[i]);
  }
  if (i == 0) offs[n] = E;
}

__global__ void place_edges(const int* __restrict__ src, const int* __restrict__ dst,
                            const float* __restrict__ dinv, int* __restrict__ cursor,
                            int* __restrict__ srcs, float* __restrict__ wsrc, int E) {
  int e = blockIdx.x * 256 + threadIdx.x;
  if (e < E) {
    int d = dst[e], s = src[e];
    int slot = atomicAdd(&cursor[d], 1);
    srcs[slot] = s;
    wsrc[slot] = dinv[s];
  }
}

__global__ void ln_stats(const float* __restrict__ x, float* __restrict__ mu,
                         float* __restrict__ rs, int n) {
  int gid = blockIdx.x * blockDim.x + threadIdx.x;
  int wv = gid >> 6, lane = gid & 63;
  if (wv >= n) return;
  const float4* row = (const float4*)(x + (size_t)wv * 256);
  float4 v = row[lane];
  float s = v.x + v.y + v.z + v.w;
  float s2 = v.x * v.x + v.y * v.y + v.z * v.z + v.w * v.w;
  for (int off = 32; off > 0; off >>= 1) {
    s += __shfl_down(s, off);
    s2 += __shfl_down(s2, off);
  }
  if (lane == 0) {
    float m = s * (1.0f / 256.0f);
    float var = s2 * (1.0f / 256.0f) - m * m;
    mu[wv] = m;
    rs[wv] = rsqrtf(var + 1e-5f);
  }
}

// W[K][NOUT] fp32 -> Wt_hi/Wt_lo[NOUT][K] bf16 bit patterns (B-operand layout)
__global__ void wsplit(const float* __restrict__ W, unsigned short* __restrict__ Wt_hi,
                       unsigned short* __restrict__ Wt_lo, int K, int NOUT) {
  int idx = blockIdx.x * 256 + threadIdx.x;
  if (idx >= K * NOUT) return;
  int k = idx / NOUT, n = idx % NOUT;
  float v = W[idx];
  __bf16 h = (__bf16)v;
  __bf16 l = (__bf16)(v - (float)h);
  Wt_hi[(size_t)n * K + k] = __builtin_bit_cast(unsigned short, h);
  Wt_lo[(size_t)n * K + k] = __builtin_bit_cast(unsigned short, l);
}

// out[nrows x NOUT] = A[nrows x K] * W[K x NOUT] via bf16x3 MFMA.
// Wt_hi/Wt_lo are [NOUT][K] bf16 (transposed, split). Optional fused LN on A.
template <int K, int NOUT, bool LN>
__launch_bounds__(256)
__global__ void gemm_mfma(const float* __restrict__ A,
                          const unsigned short* __restrict__ Wt_hi,
                          const unsigned short* __restrict__ Wt_lo,
                          const float* __restrict__ mu, const float* __restrict__ rs,
                          const float* __restrict__ gamma, const float* __restrict__ beta,
                          float* __restrict__ out, int nrows) {
  constexpr int BM = 64, BK = 32;
  constexpr int NT = NOUT / 16;  // n-tiles per wave (wave covers full NOUT)
  __shared__ unsigned short As_hi[BM][BK];
  __shared__ unsigned short As_lo[BM][BK];
  __shared__ unsigned short Bs_hi[NOUT][BK];
  __shared__ unsigned short Bs_lo[NOUT][BK];

  const int tid = threadIdx.x;
  const int lane = tid & 63;
  const int w = tid >> 6;           // wave id 0..3, handles rows w*16..w*16+15
  const int quad = lane >> 4;       // 0..3
  const int l16 = lane & 15;
  const int row0 = blockIdx.x * BM;

  f32x4 acc[NT];
#pragma unroll
  for (int t = 0; t < NT; ++t) acc[t] = (f32x4){0.f, 0.f, 0.f, 0.f};

  for (int k0 = 0; k0 < K; k0 += BK) {
    // ---- stage A (64x32 fp32 -> hi/lo bf16) ----
#pragma unroll
    for (int i = 0; i < 2; ++i) {
      int r = i * 32 + (tid >> 3);
      int c4 = (tid & 7) * 4;
      int grow = row0 + r;
      if (grow > nrows - 1) grow = nrows - 1;  // clamp (values unused)
      float4 v = *(const float4*)&A[(size_t)grow * K + k0 + c4];
      if (LN) {
        float m = mu[grow], s = rs[grow];
        float4 g = *(const float4*)&gamma[k0 + c4];
        float4 b = *(const float4*)&beta[k0 + c4];
        v.x = (v.x - m) * s * g.x + b.x;
        v.y = (v.y - m) * s * g.y + b.y;
        v.z = (v.z - m) * s * g.z + b.z;
        v.w = (v.w - m) * s * g.w + b.w;
      }
      float vv[4] = {v.x, v.y, v.z, v.w};
#pragma unroll
      for (int j = 0; j < 4; ++j) {
        __bf16 h = (__bf16)vv[j];
        __bf16 l = (__bf16)(vv[j] - (float)h);
        As_hi[r][c4 + j] = __builtin_bit_cast(unsigned short, h);
        As_lo[r][c4 + j] = __builtin_bit_cast(unsigned short, l);
      }
    }
    // ---- stage B chunk ([NOUT][32] bf16 hi/lo), 16B vector copies ----
#pragma unroll
    for (int i = 0; i < NOUT / 64; ++i) {
      int n = i * 64 + (tid >> 2);
      int c8 = (tid & 3) * 8;
      *(uint4*)&Bs_hi[n][c8] = *(const uint4*)&Wt_hi[(size_t)n * K + k0 + c8];
      *(uint4*)&Bs_lo[n][c8] = *(const uint4*)&Wt_lo[(size_t)n * K + k0 + c8];
    }
    __syncthreads();

    // ---- MFMA: each wave does 16 rows x NOUT ----
    bf16x8 ah = *(const bf16x8*)&As_hi[w * 16 + l16][quad * 8];
    bf16x8 al = *(const bf16x8*)&As_lo[w * 16 + l16][quad * 8];
#pragma unroll
    for (int t = 0; t < NT; ++t) {
      bf16x8 bh = *(const bf16x8*)&Bs_hi[t * 16 + l16][quad * 8];
      bf16x8 bl = *(const bf16x8*)&Bs_lo[t * 16 + l16][quad * 8];
      acc[t] = __builtin_amdgcn_mfma_f32_16x16x32_bf16(ah, bh, acc[t], 0, 0, 0);
      acc[t] = __builtin_amdgcn_mfma_f32_16x16x32_bf16(al, bh, acc[t], 0, 0, 0);
      acc[t] = __builtin_amdgcn_mfma_f32_16x16x32_bf16(ah, bl, acc[t], 0, 0, 0);
    }
    __syncthreads();
  }

  // ---- epilogue: D row = quad*4 + reg, col = lane&15 ----
#pragma unroll
  for (int t = 0; t < NT; ++t) {
#pragma unroll
    for (int r = 0; r < 4; ++r) {
      int grow = row0 + w * 16 + quad * 4 + r;
      if (grow < nrows) out[(size_t)grow * NOUT + t * 16 + l16] = acc[t][r];
    }
  }
}

// one wave per dst node, D=128: lane holds float2 of the feature row
template <bool RELU>
__global__ void agg128(const float* __restrict__ t, const int* __restrict__ offs,
                       const int* __restrict__ srcs, const float* __restrict__ ws,
                       const float* __restrict__ dinv, const float* __restrict__ bias,
                       float* __restrict__ out, int n) {
  int gid = blockIdx.x * blockDim.x + threadIdx.x;
  int wv = gid >> 6, lane = gid & 63;
  if (wv >= n) return;
  int e0 = offs[wv], e1 = offs[wv + 1];
  float ax = 0.f, ay = 0.f;
  for (int e = e0; e < e1; ++e) {
    int s = srcs[e];
    float w = ws[e];
    const float2 v = *(const float2*)(t + ((size_t)s << 7) + lane * 2);
    ax = fmaf(w, v.x, ax);
    ay = fmaf(w, v.y, ay);
  }
  float di = dinv[wv];
  const float2 sv = *(const float2*)(t + ((size_t)wv << 7) + lane * 2);
  const float2 bv = *(const float2*)(bias + lane * 2);
  float ox = di * ax + di * di * sv.x + bv.x;
  float oy = di * ay + di * di * sv.y + bv.y;
  if (RELU) { ox = fmaxf(ox, 0.f); oy = fmaxf(oy, 0.f); }
  float2 o = {ox, oy};
  *(float2*)(out + ((size_t)wv << 7) + lane * 2) = o;
}

// one wave per dst node, D=64: lane holds one float
template <bool RELU>
__global__ void agg64(const float* __restrict__ t, const int* __restrict__ offs,
                      const int* __restrict__ srcs, const float* __restrict__ ws,
                      const float* __restrict__ dinv, const float* __restrict__ bias,
                      float* __restrict__ out, int n) {
  int gid = blockIdx.x * blockDim.x + threadIdx.x;
  int wv = gid >> 6, lane = gid & 63;
  if (wv >= n) return;
  int e0 = offs[wv], e1 = offs[wv + 1];
  float a = 0.f;
  for (int e = e0; e < e1; ++e) {
    int s = srcs[e];
    float w = ws[e];
    a = fmaf(w, t[((size_t)s << 6) + lane], a);
  }
  float di = dinv[wv];
  float v = di * a + di * di * t[((size_t)wv << 6) + lane] + bias[lane];
  if (RELU) v = fmaxf(v, 0.f);
  out[((size_t)wv << 6) + lane] = v;
}

extern "C" void kernel_launch(void* const* d_in, const int* in_sizes, int n_in,
                              void* d_out, int out_size, void* d_ws, size_t ws_size,
                              hipStream_t stream) {
  const float* x = (const float*)d_in[0];
  const int* ei = (const int*)d_in[1];
  const float* gamma = (const float*)d_in[2];
  const float* beta = (const float*)d_in[3];
  const float* W1 = (const float*)d_in[4];
  const float* b1 = (const float*)d_in[5];
  const float* W2 = (const float*)d_in[6];
  const float* b2 = (const float*)d_in[7];
  const float* W3 = (const float*)d_in[8];
  const float* b3 = (const float*)d_in[9];
  float* out = (float*)d_out;

  const int N = in_sizes[0] / 256;
  const int E = in_sizes[1] / 2;
  const int* src = ei;
  const int* dst = ei + E;

  char* ws = (char*)d_ws;
  auto alloc = [&](size_t bytes) -> char* {
    char* p = ws;
    ws += (bytes + 255) & ~(size_t)255;
    return p;
  };
  int* cnt = (int*)alloc((size_t)N * 4);
  int* loc = (int*)alloc((size_t)N * 4);
  int* bsum = (int*)alloc(1024 * 4);
  int* offs = (int*)alloc((size_t)(N + 1) * 4);
  int* cursor = (int*)alloc((size_t)N * 4);
  float* dinv = (float*)alloc((size_t)N * 4);
  int* srcs = (int*)alloc((size_t)E * 4);
  float* wsrc = (float*)alloc((size_t)E * 4);
  float* mu = (float*)alloc((size_t)N * 4);
  float* rs = (float*)alloc((size_t)N * 4);
  float* t = (float*)alloc((size_t)N * 128 * 4);
  float* h = (float*)alloc((size_t)N * 128 * 4);
  unsigned short* W1t_hi = (unsigned short*)alloc(256 * 128 * 2);
  unsigned short* W1t_lo = (unsigned short*)alloc(256 * 128 * 2);
  unsigned short* W2t_hi = (unsigned short*)alloc(128 * 128 * 2);
  unsigned short* W2t_lo = (unsigned short*)alloc(128 * 128 * 2);
  unsigned short* W3t_hi = (unsigned short*)alloc(128 * 64 * 2);
  unsigned short* W3t_lo = (unsigned short*)alloc(128 * 64 * 2);

  const int nb1024 = (N + 1023) / 1024;

  // ---- CSR build ----
  zero_i32<<<(N + 255) / 256, 256, 0, stream>>>(cnt, N);
  count_deg<<<(E + 255) / 256, 256, 0, stream>>>(dst, cnt, E);
  scan_local<<<nb1024, 1024, 0, stream>>>(cnt, loc, bsum, N);
  scan_spine<<<1, 64, 0, stream>>>(bsum, nb1024);
  finalize_csr<<<(N + 255) / 256, 256, 0, stream>>>(cnt, loc, bsum, offs, cursor, dinv, N, E);
  place_edges<<<(E + 255) / 256, 256, 0, stream>>>(src, dst, dinv, cursor, srcs, wsrc, E);

  // ---- weight transpose + bf16 hi/lo split ----
  wsplit<<<(256 * 128 + 255) / 256, 256, 0, stream>>>(W1, W1t_hi, W1t_lo, 256, 128);
  wsplit<<<(128 * 128 + 255) / 256, 256, 0, stream>>>(W2, W2t_hi, W2t_lo, 128, 128);
  wsplit<<<(128 * 64 + 255) / 256, 256, 0, stream>>>(W3, W3t_hi, W3t_lo, 128, 64);

  // ---- layernorm stats ----
  ln_stats<<<(N + 3) / 4, 256, 0, stream>>>(x, mu, rs, N);

  const int gemm_blocks = (N + 63) / 64;
  const int agg_blocks = (N + 3) / 4;  // 4 waves per 256-thread block

  // ---- layer 1: t = LN(x) @ W1 ; h = relu(agg(t) + b1) ----
  gemm_mfma<256, 128, true><<<gemm_blocks, 256, 0, stream>>>(
      x, W1t_hi, W1t_lo, mu, rs, gamma, beta, t, N);
  agg128<true><<<agg_blocks, 256, 0, stream>>>(t, offs, srcs, wsrc, dinv, b1, h, N);

  // ---- layer 2: t = h @ W2 ; h = relu(agg(t) + b2) ----
  gemm_mfma<128, 128, false><<<gemm_blocks, 256, 0, stream>>>(
      h, W2t_hi, W2t_lo, nullptr, nullptr, nullptr, nullptr, t, N);
  agg128<true><<<agg_blocks, 256, 0, stream>>>(t, offs, srcs, wsrc, dinv, b2, h, N);

  // ---- layer 3: t = h @ W3 ; out = agg(t) + b3 ----
  gemm_mfma<128, 64, false><<<gemm_blocks, 256, 0, stream>>>(
      h, W3t_hi, W3t_lo, nullptr, nullptr, nullptr, nullptr, t, N);
  agg64<false><<<agg_blocks, 256, 0, stream>>>(t, offs, srcs, wsrc, dinv, b3, out, N);
}

// Round 3
// 417.555 us; speedup vs baseline: 1.6341x; 1.2395x over previous
//
#include <hip/hip_runtime.h>
#include <cstdint>
#include <cstddef>

// ---------------------------------------------------------------------------
// GCN encoder: z = GCN3( relu(GCN2( relu(GCN1( LN(x) )) )) )
// R3: inter-layer features stored fp16 (halves gather traffic, the R2
//     bottleneck); edge records packed int2 {src, dinv[src]}; edge loop
//     unrolled x2. GEMMs remain bf16x3 split-precision MFMA.
// ---------------------------------------------------------------------------

typedef __attribute__((ext_vector_type(8))) __bf16 bf16x8;
typedef __attribute__((ext_vector_type(4))) float f32x4;
typedef _Float16 half_t;
typedef __attribute__((ext_vector_type(2))) _Float16 half2_t;
typedef __attribute__((ext_vector_type(8))) _Float16 half8_t;

__global__ void zero_i32(int* __restrict__ p, int n) {
  int i = blockIdx.x * 256 + threadIdx.x;
  if (i < n) p[i] = 0;
}

__global__ void count_deg(const int* __restrict__ dst, int* __restrict__ cnt, int E) {
  int e = blockIdx.x * 256 + threadIdx.x;
  if (e < E) atomicAdd(&cnt[dst[e]], 1);
}

__global__ void scan_local(const int* __restrict__ cnt, int* __restrict__ loc,
                           int* __restrict__ bsum, int n) {
  __shared__ int tmp[1024];
  int tid = threadIdx.x;
  int gid = blockIdx.x * 1024 + tid;
  int v = (gid < n) ? cnt[gid] : 0;
  tmp[tid] = v;
  __syncthreads();
  for (int off = 1; off < 1024; off <<= 1) {
    int t = (tid >= off) ? tmp[tid - off] : 0;
    __syncthreads();
    tmp[tid] += t;
    __syncthreads();
  }
  if (gid < n) loc[gid] = tmp[tid] - v;  // exclusive
  if (tid == 1023) bsum[blockIdx.x] = tmp[1023];
}

__global__ void scan_spine(int* __restrict__ bsum, int nb) {
  if (threadIdx.x == 0 && blockIdx.x == 0) {
    int run = 0;
    for (int i = 0; i < nb; ++i) { int v = bsum[i]; bsum[i] = run; run += v; }
  }
}

__global__ void finalize_csr(const int* __restrict__ cnt, const int* __restrict__ loc,
                             const int* __restrict__ bsum, int* __restrict__ offs,
                             int* __restrict__ cursor, float* __restrict__ dinv,
                             int n, int E) {
  int i = blockIdx.x * 256 + threadIdx.x;
  if (i < n) {
    int o = loc[i] + bsum[i >> 10];
    offs[i] = o;
    cursor[i] = o;
    dinv[i] = rsqrtf(1.0f + (float)cnt[i]);
  }
  if (i == 0) offs[n] = E;
}

__global__ void place_edges(const int* __restrict__ src, const int* __restrict__ dst,
                            const float* __restrict__ dinv, int* __restrict__ cursor,
                            int2* __restrict__ edges, int E) {
  int e = blockIdx.x * 256 + threadIdx.x;
  if (e < E) {
    int d = dst[e], s = src[e];
    int slot = atomicAdd(&cursor[d], 1);
    edges[slot] = make_int2(s, __float_as_int(dinv[s]));
  }
}

__global__ void ln_stats(const float* __restrict__ x, float* __restrict__ mu,
                         float* __restrict__ rs, int n) {
  int gid = blockIdx.x * blockDim.x + threadIdx.x;
  int wv = gid >> 6, lane = gid & 63;
  if (wv >= n) return;
  const float4* row = (const float4*)(x + (size_t)wv * 256);
  float4 v = row[lane];
  float s = v.x + v.y + v.z + v.w;
  float s2 = v.x * v.x + v.y * v.y + v.z * v.z + v.w * v.w;
  for (int off = 32; off > 0; off >>= 1) {
    s += __shfl_down(s, off);
    s2 += __shfl_down(s2, off);
  }
  if (lane == 0) {
    float m = s * (1.0f / 256.0f);
    float var = s2 * (1.0f / 256.0f) - m * m;
    mu[wv] = m;
    rs[wv] = rsqrtf(var + 1e-5f);
  }
}

// W[K][NOUT] fp32 -> Wt_hi/Wt_lo[NOUT][K] bf16 bit patterns (B-operand layout)
__global__ void wsplit(const float* __restrict__ W, unsigned short* __restrict__ Wt_hi,
                       unsigned short* __restrict__ Wt_lo, int K, int NOUT) {
  int idx = blockIdx.x * 256 + threadIdx.x;
  if (idx >= K * NOUT) return;
  int k = idx / NOUT, n = idx % NOUT;
  float v = W[idx];
  __bf16 h = (__bf16)v;
  __bf16 l = (__bf16)(v - (float)h);
  Wt_hi[(size_t)n * K + k] = __builtin_bit_cast(unsigned short, h);
  Wt_lo[(size_t)n * K + k] = __builtin_bit_cast(unsigned short, l);
}

// out16[nrows x NOUT] = A[nrows x K] * W[K x NOUT] via bf16x3 MFMA.
// A is fp32 (with fused LN) when !A_FP16, else fp16. Output fp16.
template <int K, int NOUT, bool LN, bool A_FP16>
__launch_bounds__(256)
__global__ void gemm_mfma(const void* __restrict__ Avoid,
                          const unsigned short* __restrict__ Wt_hi,
                          const unsigned short* __restrict__ Wt_lo,
                          const float* __restrict__ mu, const float* __restrict__ rs,
                          const float* __restrict__ gamma, const float* __restrict__ beta,
                          half_t* __restrict__ out, int nrows) {
  constexpr int BM = 64, BK = 32;
  constexpr int NT = NOUT / 16;  // n-tiles per wave (wave covers full NOUT)
  __shared__ unsigned short As_hi[BM][BK];
  __shared__ unsigned short As_lo[BM][BK];
  __shared__ unsigned short Bs_hi[NOUT][BK];
  __shared__ unsigned short Bs_lo[NOUT][BK];

  const int tid = threadIdx.x;
  const int lane = tid & 63;
  const int w = tid >> 6;           // wave id 0..3, handles rows w*16..w*16+15
  const int quad = lane >> 4;       // 0..3
  const int l16 = lane & 15;
  const int row0 = blockIdx.x * BM;

  f32x4 acc[NT];
#pragma unroll
  for (int t = 0; t < NT; ++t) acc[t] = (f32x4){0.f, 0.f, 0.f, 0.f};

  for (int k0 = 0; k0 < K; k0 += BK) {
    if (!A_FP16) {
      const float* A = (const float*)Avoid;
#pragma unroll
      for (int i = 0; i < 2; ++i) {
        int r = i * 32 + (tid >> 3);
        int c4 = (tid & 7) * 4;
        int grow = row0 + r;
        if (grow > nrows - 1) grow = nrows - 1;  // clamp (values unused)
        float4 v = *(const float4*)&A[(size_t)grow * K + k0 + c4];
        if (LN) {
          float m = mu[grow], s = rs[grow];
          float4 g = *(const float4*)&gamma[k0 + c4];
          float4 b = *(const float4*)&beta[k0 + c4];
          v.x = (v.x - m) * s * g.x + b.x;
          v.y = (v.y - m) * s * g.y + b.y;
          v.z = (v.z - m) * s * g.z + b.z;
          v.w = (v.w - m) * s * g.w + b.w;
        }
        float vv[4] = {v.x, v.y, v.z, v.w};
#pragma unroll
        for (int j = 0; j < 4; ++j) {
          __bf16 h = (__bf16)vv[j];
          __bf16 l = (__bf16)(vv[j] - (float)h);
          As_hi[r][c4 + j] = __builtin_bit_cast(unsigned short, h);
          As_lo[r][c4 + j] = __builtin_bit_cast(unsigned short, l);
        }
      }
    } else {
      const half_t* A = (const half_t*)Avoid;
      int r = tid >> 2;            // 0..63
      int c8 = (tid & 3) * 8;      // 0,8,16,24
      int grow = row0 + r;
      if (grow > nrows - 1) grow = nrows - 1;
      half8_t v = *(const half8_t*)&A[(size_t)grow * K + k0 + c8];
#pragma unroll
      for (int j = 0; j < 8; ++j) {
        float f = (float)v[j];
        __bf16 h = (__bf16)f;
        __bf16 l = (__bf16)(f - (float)h);
        As_hi[r][c8 + j] = __builtin_bit_cast(unsigned short, h);
        As_lo[r][c8 + j] = __builtin_bit_cast(unsigned short, l);
      }
    }
    // ---- stage B chunk ([NOUT][32] bf16 hi/lo), 16B vector copies ----
#pragma unroll
    for (int i = 0; i < NOUT / 64; ++i) {
      int n = i * 64 + (tid >> 2);
      int c8 = (tid & 3) * 8;
      *(uint4*)&Bs_hi[n][c8] = *(const uint4*)&Wt_hi[(size_t)n * K + k0 + c8];
      *(uint4*)&Bs_lo[n][c8] = *(const uint4*)&Wt_lo[(size_t)n * K + k0 + c8];
    }
    __syncthreads();

    // ---- MFMA: each wave does 16 rows x NOUT ----
    bf16x8 ah = *(const bf16x8*)&As_hi[w * 16 + l16][quad * 8];
    bf16x8 al = *(const bf16x8*)&As_lo[w * 16 + l16][quad * 8];
#pragma unroll
    for (int t = 0; t < NT; ++t) {
      bf16x8 bh = *(const bf16x8*)&Bs_hi[t * 16 + l16][quad * 8];
      bf16x8 bl = *(const bf16x8*)&Bs_lo[t * 16 + l16][quad * 8];
      acc[t] = __builtin_amdgcn_mfma_f32_16x16x32_bf16(ah, bh, acc[t], 0, 0, 0);
      acc[t] = __builtin_amdgcn_mfma_f32_16x16x32_bf16(al, bh, acc[t], 0, 0, 0);
      acc[t] = __builtin_amdgcn_mfma_f32_16x16x32_bf16(ah, bl, acc[t], 0, 0, 0);
    }
    __syncthreads();
  }

  // ---- epilogue: D row = quad*4 + reg, col = lane&15 ----
#pragma unroll
  for (int t = 0; t < NT; ++t) {
#pragma unroll
    for (int r = 0; r < 4; ++r) {
      int grow = row0 + w * 16 + quad * 4 + r;
      if (grow < nrows) out[(size_t)grow * NOUT + t * 16 + l16] = (half_t)acc[t][r];
    }
  }
}

// one wave per dst node, D=128 fp16: lane holds half2 of the feature row
__global__ void agg128_h(const half_t* __restrict__ t, const int* __restrict__ offs,
                         const int2* __restrict__ edges, const float* __restrict__ dinv,
                         const float* __restrict__ bias, half_t* __restrict__ out, int n) {
  int gid = blockIdx.x * blockDim.x + threadIdx.x;
  int wv = gid >> 6, lane = gid & 63;
  if (wv >= n) return;
  int e0 = offs[wv], e1 = offs[wv + 1];
  float ax = 0.f, ay = 0.f;
  int e = e0;
  for (; e + 1 < e1; e += 2) {
    int2 ed0 = edges[e];
    int2 ed1 = edges[e + 1];
    half2_t v0 = *(const half2_t*)(t + ((size_t)ed0.x << 7) + lane * 2);
    half2_t v1 = *(const half2_t*)(t + ((size_t)ed1.x << 7) + lane * 2);
    float w0 = __int_as_float(ed0.y), w1 = __int_as_float(ed1.y);
    ax = fmaf(w0, (float)v0[0], ax);
    ay = fmaf(w0, (float)v0[1], ay);
    ax = fmaf(w1, (float)v1[0], ax);
    ay = fmaf(w1, (float)v1[1], ay);
  }
  if (e < e1) {
    int2 ed = edges[e];
    half2_t v = *(const half2_t*)(t + ((size_t)ed.x << 7) + lane * 2);
    float w = __int_as_float(ed.y);
    ax = fmaf(w, (float)v[0], ax);
    ay = fmaf(w, (float)v[1], ay);
  }
  float di = dinv[wv];
  half2_t sv = *(const half2_t*)(t + ((size_t)wv << 7) + lane * 2);
  float2 bv = *(const float2*)(bias + lane * 2);
  float ox = di * ax + di * di * (float)sv[0] + bv.x;
  float oy = di * ay + di * di * (float)sv[1] + bv.y;
  ox = fmaxf(ox, 0.f);
  oy = fmaxf(oy, 0.f);
  half2_t o;
  o[0] = (half_t)ox;
  o[1] = (half_t)oy;
  *(half2_t*)(out + ((size_t)wv << 7) + lane * 2) = o;
}

// one wave per dst node, D=64 fp16 in, fp32 out (final layer, no relu)
__global__ void agg64_h(const half_t* __restrict__ t, const int* __restrict__ offs,
                        const int2* __restrict__ edges, const float* __restrict__ dinv,
                        const float* __restrict__ bias, float* __restrict__ out, int n) {
  int gid = blockIdx.x * blockDim.x + threadIdx.x;
  int wv = gid >> 6, lane = gid & 63;
  if (wv >= n) return;
  int e0 = offs[wv], e1 = offs[wv + 1];
  float a = 0.f;
  int e = e0;
  for (; e + 1 < e1; e += 2) {
    int2 ed0 = edges[e];
    int2 ed1 = edges[e + 1];
    float v0 = (float)t[((size_t)ed0.x << 6) + lane];
    float v1 = (float)t[((size_t)ed1.x << 6) + lane];
    a = fmaf(__int_as_float(ed0.y), v0, a);
    a = fmaf(__int_as_float(ed1.y), v1, a);
  }
  if (e < e1) {
    int2 ed = edges[e];
    a = fmaf(__int_as_float(ed.y), (float)t[((size_t)ed.x << 6) + lane], a);
  }
  float di = dinv[wv];
  float v = di * a + di * di * (float)t[((size_t)wv << 6) + lane] + bias[lane];
  out[((size_t)wv << 6) + lane] = v;
}

extern "C" void kernel_launch(void* const* d_in, const int* in_sizes, int n_in,
                              void* d_out, int out_size, void* d_ws, size_t ws_size,
                              hipStream_t stream) {
  const float* x = (const float*)d_in[0];
  const int* ei = (const int*)d_in[1];
  const float* gamma = (const float*)d_in[2];
  const float* beta = (const float*)d_in[3];
  const float* W1 = (const float*)d_in[4];
  const float* b1 = (const float*)d_in[5];
  const float* W2 = (const float*)d_in[6];
  const float* b2 = (const float*)d_in[7];
  const float* W3 = (const float*)d_in[8];
  const float* b3 = (const float*)d_in[9];
  float* out = (float*)d_out;

  const int N = in_sizes[0] / 256;
  const int E = in_sizes[1] / 2;
  const int* src = ei;
  const int* dst = ei + E;

  char* ws = (char*)d_ws;
  auto alloc = [&](size_t bytes) -> char* {
    char* p = ws;
    ws += (bytes + 255) & ~(size_t)255;
    return p;
  };
  int* cnt = (int*)alloc((size_t)N * 4);
  int* loc = (int*)alloc((size_t)N * 4);
  int* bsum = (int*)alloc(1024 * 4);
  int* offs = (int*)alloc((size_t)(N + 1) * 4);
  int* cursor = (int*)alloc((size_t)N * 4);
  float* dinv = (float*)alloc((size_t)N * 4);
  int2* edges = (int2*)alloc((size_t)E * 8);
  float* mu = (float*)alloc((size_t)N * 4);
  float* rs = (float*)alloc((size_t)N * 4);
  half_t* t = (half_t*)alloc((size_t)N * 128 * 2);
  half_t* h = (half_t*)alloc((size_t)N * 128 * 2);
  unsigned short* W1t_hi = (unsigned short*)alloc(256 * 128 * 2);
  unsigned short* W1t_lo = (unsigned short*)alloc(256 * 128 * 2);
  unsigned short* W2t_hi = (unsigned short*)alloc(128 * 128 * 2);
  unsigned short* W2t_lo = (unsigned short*)alloc(128 * 128 * 2);
  unsigned short* W3t_hi = (unsigned short*)alloc(128 * 64 * 2);
  unsigned short* W3t_lo = (unsigned short*)alloc(128 * 64 * 2);

  const int nb1024 = (N + 1023) / 1024;

  // ---- CSR build ----
  zero_i32<<<(N + 255) / 256, 256, 0, stream>>>(cnt, N);
  count_deg<<<(E + 255) / 256, 256, 0, stream>>>(dst, cnt, E);
  scan_local<<<nb1024, 1024, 0, stream>>>(cnt, loc, bsum, N);
  scan_spine<<<1, 64, 0, stream>>>(bsum, nb1024);
  finalize_csr<<<(N + 255) / 256, 256, 0, stream>>>(cnt, loc, bsum, offs, cursor, dinv, N, E);
  place_edges<<<(E + 255) / 256, 256, 0, stream>>>(src, dst, dinv, cursor, edges, E);

  // ---- weight transpose + bf16 hi/lo split ----
  wsplit<<<(256 * 128 + 255) / 256, 256, 0, stream>>>(W1, W1t_hi, W1t_lo, 256, 128);
  wsplit<<<(128 * 128 + 255) / 256, 256, 0, stream>>>(W2, W2t_hi, W2t_lo, 128, 128);
  wsplit<<<(128 * 64 + 255) / 256, 256, 0, stream>>>(W3, W3t_hi, W3t_lo, 128, 64);

  // ---- layernorm stats ----
  ln_stats<<<(N + 3) / 4, 256, 0, stream>>>(x, mu, rs, N);

  const int gemm_blocks = (N + 63) / 64;
  const int agg_blocks = (N + 3) / 4;  // 4 waves per 256-thread block

  // ---- layer 1: t = LN(x) @ W1 ; h = relu(agg(t) + b1) ----
  gemm_mfma<256, 128, true, false><<<gemm_blocks, 256, 0, stream>>>(
      x, W1t_hi, W1t_lo, mu, rs, gamma, beta, t, N);
  agg128_h<<<agg_blocks, 256, 0, stream>>>(t, offs, edges, dinv, b1, h, N);

  // ---- layer 2: t = h @ W2 ; h = relu(agg(t) + b2) ----
  gemm_mfma<128, 128, false, true><<<gemm_blocks, 256, 0, stream>>>(
      h, W2t_hi, W2t_lo, nullptr, nullptr, nullptr, nullptr, t, N);
  agg128_h<<<agg_blocks, 256, 0, stream>>>(t, offs, edges, dinv, b2, h, N);

  // ---- layer 3: t = h @ W3 ; out = agg(t) + b3 ----
  gemm_mfma<128, 64, false, true><<<gemm_blocks, 256, 0, stream>>>(
      h, W3t_hi, W3t_lo, nullptr, nullptr, nullptr, nullptr, t, N);
  agg64_h<<<agg_blocks, 256, 0, stream>>>(t, offs, edges, dinv, b3, out, N);
}

// Round 4
// 326.064 us; speedup vs baseline: 2.0926x; 1.2806x over previous
//
#include <hip/hip_runtime.h>
#include <cstdint>
#include <cstddef>

// ---------------------------------------------------------------------------
// GCN encoder: z = GCN3( relu(GCN2( relu(GCN1( LN(x) )) )) )
// R4: CSR build replaced by 2-level LDS bucket sort (kills the 52 MB scatter
//     write-amplification of place_edges + all atomic counting kernels).
//     Agg edge loops unrolled x4 for gather MLP. GEMMs: bf16x3 MFMA.
// ---------------------------------------------------------------------------

typedef __attribute__((ext_vector_type(8))) __bf16 bf16x8;
typedef __attribute__((ext_vector_type(4))) float f32x4;
typedef _Float16 half_t;
typedef __attribute__((ext_vector_type(2))) _Float16 half2_t;
typedef __attribute__((ext_vector_type(8))) _Float16 half8_t;

// ---------------- CSR build: bucket sort by dst ----------------
// bucket b = dst >> 8 (256 nodes per bucket); NB = ceil(N/256) = 196.

__global__ void zero_ctl(int* __restrict__ p, int n) {
  int i = blockIdx.x * 256 + threadIdx.x;
  if (i < n) p[i] = 0;
}

__global__ __launch_bounds__(256) void hist_bucket(const int* __restrict__ dst,
                                                   int* __restrict__ bcnt, int E, int NB) {
  __shared__ int h[256];
  int t = threadIdx.x;
  h[t] = 0;
  __syncthreads();
  for (int e = blockIdx.x * 256 + t; e < E; e += gridDim.x * 256)
    atomicAdd(&h[dst[e] >> 8], 1);
  __syncthreads();
  if (t < NB && h[t]) atomicAdd(&bcnt[t], h[t]);
}

__global__ __launch_bounds__(256) void scan_buckets(const int* __restrict__ bcnt,
                                                    int* __restrict__ bbase,
                                                    int* __restrict__ bcur, int NB, int E) {
  __shared__ int tmp[256];
  int t = threadIdx.x;
  int v = (t < NB) ? bcnt[t] : 0;
  tmp[t] = v;
  __syncthreads();
  for (int off = 1; off < 256; off <<= 1) {
    int x = (t >= off) ? tmp[t - off] : 0;
    __syncthreads();
    tmp[t] += x;
    __syncthreads();
  }
  int excl = tmp[t] - v;
  if (t < NB) { bbase[t] = excl; bcur[t] = excl; }
  if (t == 0) bbase[NB] = E;
}

#define CHUNK 4096
__global__ __launch_bounds__(256) void scatter_bins(const int* __restrict__ src,
                                                    const int* __restrict__ dst,
                                                    int* __restrict__ bcur,
                                                    int2* __restrict__ binned, int E) {
  __shared__ int2 recs[CHUNK];
  __shared__ int hist[256], lbase[256], resv[256], cur[256];
  int t = threadIdx.x;
  int e0 = blockIdx.x * CHUNK;
  if (e0 >= E) return;
  int len = min(CHUNK, E - e0);
  hist[t] = 0;
  cur[t] = 0;
  __syncthreads();
  for (int i = t; i < len; i += 256) atomicAdd(&hist[dst[e0 + i] >> 8], 1);
  __syncthreads();
  int v = hist[t];
  lbase[t] = v;
  __syncthreads();
  for (int off = 1; off < 256; off <<= 1) {
    int x = (t >= off) ? lbase[t - off] : 0;
    __syncthreads();
    lbase[t] += x;
    __syncthreads();
  }
  int myexcl = lbase[t] - v;
  if (v) resv[t] = atomicAdd(&bcur[t], v);  // reserve contiguous range per bucket
  __syncthreads();
  lbase[t] = myexcl;
  __syncthreads();
  // place records into LDS ordered by bucket
  for (int i = t; i < len; i += 256) {
    int d = dst[e0 + i], s = src[e0 + i];
    int b = d >> 8;
    int r = atomicAdd(&cur[b], 1);
    recs[lbase[b] + r] = make_int2(s, d);
  }
  __syncthreads();
  // flush: bucket-contiguous runs -> near-coalesced global writes
  for (int i = t; i < len; i += 256) {
    int2 rc = recs[i];
    int b = rc.y >> 8;
    binned[resv[b] + (i - lbase[b])] = rc;
  }
}

#define MAXB 8192
__global__ __launch_bounds__(256) void sort_bucket(const int2* __restrict__ binned,
                                                   const int* __restrict__ bbase,
                                                   int* __restrict__ srcs,
                                                   int* __restrict__ offs,
                                                   float* __restrict__ dinv,
                                                   int N, int NB, int E) {
  __shared__ int2 recs[MAXB];           // 64 KB
  __shared__ unsigned short rnk[MAXB];  // 16 KB
  __shared__ int sstage[MAXB];          // 32 KB
  __shared__ int hist[256], nbase[256];
  int b = blockIdx.x, t = threadIdx.x;
  int base = bbase[b], end = bbase[b + 1];
  int L = end - base;
  if (L > MAXB) L = MAXB;  // safety (statistically impossible for random dst)
  hist[t] = 0;
  __syncthreads();
  for (int i = t; i < L; i += 256) {
    int2 rc = binned[base + i];
    recs[i] = rc;
    int r = atomicAdd(&hist[rc.y & 255], 1);
    rnk[i] = (unsigned short)r;
  }
  __syncthreads();
  int v = hist[t];
  nbase[t] = v;
  __syncthreads();
  for (int off = 1; off < 256; off <<= 1) {
    int x = (t >= off) ? nbase[t - off] : 0;
    __syncthreads();
    nbase[t] += x;
    __syncthreads();
  }
  int excl = nbase[t] - v;
  __syncthreads();
  nbase[t] = excl;
  int node = (b << 8) + t;
  if (node < N) {
    offs[node] = base + excl;
    dinv[node] = rsqrtf(1.0f + (float)v);
  }
  if (b == NB - 1 && t == 0) offs[N] = E;
  __syncthreads();
  for (int i = t; i < L; i += 256) {
    int2 rc = recs[i];
    sstage[nbase[rc.y & 255] + rnk[i]] = rc.x;
  }
  __syncthreads();
  for (int i = t; i < L; i += 256) srcs[base + i] = sstage[i];
}

__global__ void fill_w(const int* __restrict__ srcs, const float* __restrict__ dinv,
                       int2* __restrict__ edges, int E) {
  int e = blockIdx.x * 256 + threadIdx.x;
  if (e < E) {
    int s = srcs[e];
    edges[e] = make_int2(s, __float_as_int(dinv[s]));
  }
}

// ---------------- LN stats ----------------
__global__ void ln_stats(const float* __restrict__ x, float* __restrict__ mu,
                         float* __restrict__ rs, int n) {
  int gid = blockIdx.x * blockDim.x + threadIdx.x;
  int wv = gid >> 6, lane = gid & 63;
  if (wv >= n) return;
  const float4* row = (const float4*)(x + (size_t)wv * 256);
  float4 v = row[lane];
  float s = v.x + v.y + v.z + v.w;
  float s2 = v.x * v.x + v.y * v.y + v.z * v.z + v.w * v.w;
  for (int off = 32; off > 0; off >>= 1) {
    s += __shfl_down(s, off);
    s2 += __shfl_down(s2, off);
  }
  if (lane == 0) {
    float m = s * (1.0f / 256.0f);
    float var = s2 * (1.0f / 256.0f) - m * m;
    mu[wv] = m;
    rs[wv] = rsqrtf(var + 1e-5f);
  }
}

// W[K][NOUT] fp32 -> Wt_hi/Wt_lo[NOUT][K] bf16 bit patterns (B-operand layout)
__global__ void wsplit(const float* __restrict__ W, unsigned short* __restrict__ Wt_hi,
                       unsigned short* __restrict__ Wt_lo, int K, int NOUT) {
  int idx = blockIdx.x * 256 + threadIdx.x;
  if (idx >= K * NOUT) return;
  int k = idx / NOUT, n = idx % NOUT;
  float v = W[idx];
  __bf16 h = (__bf16)v;
  __bf16 l = (__bf16)(v - (float)h);
  Wt_hi[(size_t)n * K + k] = __builtin_bit_cast(unsigned short, h);
  Wt_lo[(size_t)n * K + k] = __builtin_bit_cast(unsigned short, l);
}

// out16[nrows x NOUT] = A[nrows x K] * W[K x NOUT] via bf16x3 MFMA.
template <int K, int NOUT, bool LN, bool A_FP16>
__launch_bounds__(256)
__global__ void gemm_mfma(const void* __restrict__ Avoid,
                          const unsigned short* __restrict__ Wt_hi,
                          const unsigned short* __restrict__ Wt_lo,
                          const float* __restrict__ mu, const float* __restrict__ rs,
                          const float* __restrict__ gamma, const float* __restrict__ beta,
                          half_t* __restrict__ out, int nrows) {
  constexpr int BM = 64, BK = 32;
  constexpr int NT = NOUT / 16;
  __shared__ unsigned short As_hi[BM][BK];
  __shared__ unsigned short As_lo[BM][BK];
  __shared__ unsigned short Bs_hi[NOUT][BK];
  __shared__ unsigned short Bs_lo[NOUT][BK];

  const int tid = threadIdx.x;
  const int lane = tid & 63;
  const int w = tid >> 6;
  const int quad = lane >> 4;
  const int l16 = lane & 15;
  const int row0 = blockIdx.x * BM;

  f32x4 acc[NT];
#pragma unroll
  for (int t = 0; t < NT; ++t) acc[t] = (f32x4){0.f, 0.f, 0.f, 0.f};

  for (int k0 = 0; k0 < K; k0 += BK) {
    if (!A_FP16) {
      const float* A = (const float*)Avoid;
#pragma unroll
      for (int i = 0; i < 2; ++i) {
        int r = i * 32 + (tid >> 3);
        int c4 = (tid & 7) * 4;
        int grow = row0 + r;
        if (grow > nrows - 1) grow = nrows - 1;
        float4 v = *(const float4*)&A[(size_t)grow * K + k0 + c4];
        if (LN) {
          float m = mu[grow], s = rs[grow];
          float4 g = *(const float4*)&gamma[k0 + c4];
          float4 b = *(const float4*)&beta[k0 + c4];
          v.x = (v.x - m) * s * g.x + b.x;
          v.y = (v.y - m) * s * g.y + b.y;
          v.z = (v.z - m) * s * g.z + b.z;
          v.w = (v.w - m) * s * g.w + b.w;
        }
        float vv[4] = {v.x, v.y, v.z, v.w};
#pragma unroll
        for (int j = 0; j < 4; ++j) {
          __bf16 h = (__bf16)vv[j];
          __bf16 l = (__bf16)(vv[j] - (float)h);
          As_hi[r][c4 + j] = __builtin_bit_cast(unsigned short, h);
          As_lo[r][c4 + j] = __builtin_bit_cast(unsigned short, l);
        }
      }
    } else {
      const half_t* A = (const half_t*)Avoid;
      int r = tid >> 2;
      int c8 = (tid & 3) * 8;
      int grow = row0 + r;
      if (grow > nrows - 1) grow = nrows - 1;
      half8_t v = *(const half8_t*)&A[(size_t)grow * K + k0 + c8];
#pragma unroll
      for (int j = 0; j < 8; ++j) {
        float f = (float)v[j];
        __bf16 h = (__bf16)f;
        __bf16 l = (__bf16)(f - (float)h);
        As_hi[r][c8 + j] = __builtin_bit_cast(unsigned short, h);
        As_lo[r][c8 + j] = __builtin_bit_cast(unsigned short, l);
      }
    }
#pragma unroll
    for (int i = 0; i < NOUT / 64; ++i) {
      int n = i * 64 + (tid >> 2);
      int c8 = (tid & 3) * 8;
      *(uint4*)&Bs_hi[n][c8] = *(const uint4*)&Wt_hi[(size_t)n * K + k0 + c8];
      *(uint4*)&Bs_lo[n][c8] = *(const uint4*)&Wt_lo[(size_t)n * K + k0 + c8];
    }
    __syncthreads();

    bf16x8 ah = *(const bf16x8*)&As_hi[w * 16 + l16][quad * 8];
    bf16x8 al = *(const bf16x8*)&As_lo[w * 16 + l16][quad * 8];
#pragma unroll
    for (int t = 0; t < NT; ++t) {
      bf16x8 bh = *(const bf16x8*)&Bs_hi[t * 16 + l16][quad * 8];
      bf16x8 bl = *(const bf16x8*)&Bs_lo[t * 16 + l16][quad * 8];
      acc[t] = __builtin_amdgcn_mfma_f32_16x16x32_bf16(ah, bh, acc[t], 0, 0, 0);
      acc[t] = __builtin_amdgcn_mfma_f32_16x16x32_bf16(al, bh, acc[t], 0, 0, 0);
      acc[t] = __builtin_amdgcn_mfma_f32_16x16x32_bf16(ah, bl, acc[t], 0, 0, 0);
    }
    __syncthreads();
  }

#pragma unroll
  for (int t = 0; t < NT; ++t) {
#pragma unroll
    for (int r = 0; r < 4; ++r) {
      int grow = row0 + w * 16 + quad * 4 + r;
      if (grow < nrows) out[(size_t)grow * NOUT + t * 16 + l16] = (half_t)acc[t][r];
    }
  }
}

// ---------------- aggregation (wave per dst node, x4 unrolled gathers) ------
__global__ void agg128_h(const half_t* __restrict__ t, const int* __restrict__ offs,
                         const int2* __restrict__ edges, const float* __restrict__ dinv,
                         const float* __restrict__ bias, half_t* __restrict__ out, int n) {
  int gid = blockIdx.x * blockDim.x + threadIdx.x;
  int wv = gid >> 6, lane = gid & 63;
  if (wv >= n) return;
  int e0 = offs[wv], e1 = offs[wv + 1];
  float ax = 0.f, ay = 0.f;
  int e = e0;
  for (; e + 3 < e1; e += 4) {
    int2 d0 = edges[e], d1 = edges[e + 1], d2 = edges[e + 2], d3 = edges[e + 3];
    half2_t v0 = *(const half2_t*)(t + ((size_t)d0.x << 7) + lane * 2);
    half2_t v1 = *(const half2_t*)(t + ((size_t)d1.x << 7) + lane * 2);
    half2_t v2 = *(const half2_t*)(t + ((size_t)d2.x << 7) + lane * 2);
    half2_t v3 = *(const half2_t*)(t + ((size_t)d3.x << 7) + lane * 2);
    float w0 = __int_as_float(d0.y), w1 = __int_as_float(d1.y);
    float w2 = __int_as_float(d2.y), w3 = __int_as_float(d3.y);
    ax = fmaf(w0, (float)v0[0], ax); ay = fmaf(w0, (float)v0[1], ay);
    ax = fmaf(w1, (float)v1[0], ax); ay = fmaf(w1, (float)v1[1], ay);
    ax = fmaf(w2, (float)v2[0], ax); ay = fmaf(w2, (float)v2[1], ay);
    ax = fmaf(w3, (float)v3[0], ax); ay = fmaf(w3, (float)v3[1], ay);
  }
  for (; e < e1; ++e) {
    int2 ed = edges[e];
    half2_t v = *(const half2_t*)(t + ((size_t)ed.x << 7) + lane * 2);
    float w = __int_as_float(ed.y);
    ax = fmaf(w, (float)v[0], ax);
    ay = fmaf(w, (float)v[1], ay);
  }
  float di = dinv[wv];
  half2_t sv = *(const half2_t*)(t + ((size_t)wv << 7) + lane * 2);
  float2 bv = *(const float2*)(bias + lane * 2);
  float ox = di * ax + di * di * (float)sv[0] + bv.x;
  float oy = di * ay + di * di * (float)sv[1] + bv.y;
  ox = fmaxf(ox, 0.f);
  oy = fmaxf(oy, 0.f);
  half2_t o;
  o[0] = (half_t)ox;
  o[1] = (half_t)oy;
  *(half2_t*)(out + ((size_t)wv << 7) + lane * 2) = o;
}

__global__ void agg64_h(const half_t* __restrict__ t, const int* __restrict__ offs,
                        const int2* __restrict__ edges, const float* __restrict__ dinv,
                        const float* __restrict__ bias, float* __restrict__ out, int n) {
  int gid = blockIdx.x * blockDim.x + threadIdx.x;
  int wv = gid >> 6, lane = gid & 63;
  if (wv >= n) return;
  int e0 = offs[wv], e1 = offs[wv + 1];
  float a = 0.f;
  int e = e0;
  for (; e + 3 < e1; e += 4) {
    int2 d0 = edges[e], d1 = edges[e + 1], d2 = edges[e + 2], d3 = edges[e + 3];
    float v0 = (float)t[((size_t)d0.x << 6) + lane];
    float v1 = (float)t[((size_t)d1.x << 6) + lane];
    float v2 = (float)t[((size_t)d2.x << 6) + lane];
    float v3 = (float)t[((size_t)d3.x << 6) + lane];
    a = fmaf(__int_as_float(d0.y), v0, a);
    a = fmaf(__int_as_float(d1.y), v1, a);
    a = fmaf(__int_as_float(d2.y), v2, a);
    a = fmaf(__int_as_float(d3.y), v3, a);
  }
  for (; e < e1; ++e) {
    int2 ed = edges[e];
    a = fmaf(__int_as_float(ed.y), (float)t[((size_t)ed.x << 6) + lane], a);
  }
  float di = dinv[wv];
  float v = di * a + di * di * (float)t[((size_t)wv << 6) + lane] + bias[lane];
  out[((size_t)wv << 6) + lane] = v;
}

extern "C" void kernel_launch(void* const* d_in, const int* in_sizes, int n_in,
                              void* d_out, int out_size, void* d_ws, size_t ws_size,
                              hipStream_t stream) {
  const float* x = (const float*)d_in[0];
  const int* ei = (const int*)d_in[1];
  const float* gamma = (const float*)d_in[2];
  const float* beta = (const float*)d_in[3];
  const float* W1 = (const float*)d_in[4];
  const float* b1 = (const float*)d_in[5];
  const float* W2 = (const float*)d_in[6];
  const float* b2 = (const float*)d_in[7];
  const float* W3 = (const float*)d_in[8];
  const float* b3 = (const float*)d_in[9];
  float* out = (float*)d_out;

  const int N = in_sizes[0] / 256;
  const int E = in_sizes[1] / 2;
  const int* src = ei;
  const int* dst = ei + E;
  const int NB = (N + 255) >> 8;

  char* ws = (char*)d_ws;
  auto alloc = [&](size_t bytes) -> char* {
    char* p = ws;
    ws += (bytes + 255) & ~(size_t)255;
    return p;
  };
  int* bcnt = (int*)alloc(256 * 4);
  int* bbase = (int*)alloc(257 * 4);
  int* bcur = (int*)alloc(256 * 4);
  int2* binned = (int2*)alloc((size_t)E * 8);
  int* srcs = (int*)alloc((size_t)E * 4);
  int* offs = (int*)alloc((size_t)(N + 1) * 4);
  float* dinv = (float*)alloc((size_t)N * 4);
  int2* edges = (int2*)alloc((size_t)E * 8);
  float* mu = (float*)alloc((size_t)N * 4);
  float* rs = (float*)alloc((size_t)N * 4);
  half_t* t = (half_t*)alloc((size_t)N * 128 * 2);
  half_t* h = (half_t*)alloc((size_t)N * 128 * 2);
  unsigned short* W1t_hi = (unsigned short*)alloc(256 * 128 * 2);
  unsigned short* W1t_lo = (unsigned short*)alloc(256 * 128 * 2);
  unsigned short* W2t_hi = (unsigned short*)alloc(128 * 128 * 2);
  unsigned short* W2t_lo = (unsigned short*)alloc(128 * 128 * 2);
  unsigned short* W3t_hi = (unsigned short*)alloc(128 * 64 * 2);
  unsigned short* W3t_lo = (unsigned short*)alloc(128 * 64 * 2);

  // ---- CSR build via 2-level bucket sort ----
  zero_ctl<<<1, 256, 0, stream>>>(bcnt, 256);
  hist_bucket<<<256, 256, 0, stream>>>(dst, bcnt, E, NB);
  scan_buckets<<<1, 256, 0, stream>>>(bcnt, bbase, bcur, NB, E);
  scatter_bins<<<(E + CHUNK - 1) / CHUNK, 256, 0, stream>>>(src, dst, bcur, binned, E);
  sort_bucket<<<NB, 256, 0, stream>>>(binned, bbase, srcs, offs, dinv, N, NB, E);
  fill_w<<<(E + 255) / 256, 256, 0, stream>>>(srcs, dinv, edges, E);

  // ---- weight transpose + bf16 hi/lo split ----
  wsplit<<<(256 * 128 + 255) / 256, 256, 0, stream>>>(W1, W1t_hi, W1t_lo, 256, 128);
  wsplit<<<(128 * 128 + 255) / 256, 256, 0, stream>>>(W2, W2t_hi, W2t_lo, 128, 128);
  wsplit<<<(128 * 64 + 255) / 256, 256, 0, stream>>>(W3, W3t_hi, W3t_lo, 128, 64);

  // ---- layernorm stats ----
  ln_stats<<<(N + 3) / 4, 256, 0, stream>>>(x, mu, rs, N);

  const int gemm_blocks = (N + 63) / 64;
  const int agg_blocks = (N + 3) / 4;

  // ---- layer 1 ----
  gemm_mfma<256, 128, true, false><<<gemm_blocks, 256, 0, stream>>>(
      x, W1t_hi, W1t_lo, mu, rs, gamma, beta, t, N);
  agg128_h<<<agg_blocks, 256, 0, stream>>>(t, offs, edges, dinv, b1, h, N);

  // ---- layer 2 ----
  gemm_mfma<128, 128, false, true><<<gemm_blocks, 256, 0, stream>>>(
      h, W2t_hi, W2t_lo, nullptr, nullptr, nullptr, nullptr, t, N);
  agg128_h<<<agg_blocks, 256, 0, stream>>>(t, offs, edges, dinv, b2, h, N);

  // ---- layer 3 ----
  gemm_mfma<128, 64, false, true><<<gemm_blocks, 256, 0, stream>>>(
      h, W3t_hi, W3t_lo, nullptr, nullptr, nullptr, nullptr, t, N);
  agg64_h<<<agg_blocks, 256, 0, stream>>>(t, offs, edges, dinv, b3, out, N);
}